// Round 11
// baseline (172.353 us; speedup 1.0000x reference)
//
#include <hip/hip_runtime.h>
#include <math.h>

static constexpr int Bn = 8, Ln = 1024, Dm = 512, Hn = 8, DhN = 64;

typedef short bf16x8 __attribute__((ext_vector_type(8)));
typedef float f32x4 __attribute__((ext_vector_type(4)));
typedef _Float16 f16x4 __attribute__((ext_vector_type(4)));
typedef _Float16 f16x8 __attribute__((ext_vector_type(8)));
typedef unsigned int u32x4 __attribute__((ext_vector_type(4)));

// 0.125 * log2(e): folds the 1/sqrt(dh) scale AND the exp->exp2 conversion
#define QSCALE 0.1803368801111137f

static __device__ __forceinline__ unsigned short f2b(float f) {
  union { float f; unsigned int u; } x;
  x.f = f;
  unsigned int u = x.u;
  unsigned int r = (u + 0x7FFFu + ((u >> 16) & 1u)) >> 16;  // RNE
  return (unsigned short)r;
}
static __device__ __forceinline__ float b2f(unsigned short u) {
  union { unsigned int u; float f; } x;
  x.u = ((unsigned int)u) << 16;
  return x.f;
}

#define GLDS16(g, l)                                                        \
  __builtin_amdgcn_global_load_lds((const __attribute__((address_space(1))) void*)(g), \
                                   (__attribute__((address_space(3))) void*)(l), 16, 0, 0)

// ---------------- prep1: LayerNorm + PE + weight conversions (one dispatch) ----------------
__global__ __launch_bounds__(256) void prep1(const float* __restrict__ x,
                                             const float* __restrict__ gamma,
                                             const float* __restrict__ beta,
                                             unsigned short* __restrict__ xn,
                                             unsigned short* __restrict__ pe,
                                             const float* __restrict__ wq, unsigned short* __restrict__ wqb,
                                             const float* __restrict__ wp, unsigned short* __restrict__ wpb,
                                             const float* __restrict__ wo, unsigned short* __restrict__ wob) {
  int b = blockIdx.x;
  int t = threadIdx.x;
  if (b < 8192) {
    // LayerNorm row b
    const float2 v = *(const float2*)(x + (size_t)b * Dm + t * 2);
    float s = v.x + v.y;
    float sq = v.x * v.x + v.y * v.y;
#pragma unroll
    for (int off = 32; off > 0; off >>= 1) {
      s += __shfl_down(s, off);
      sq += __shfl_down(sq, off);
    }
    __shared__ float red[8];
    int wave = t >> 6, lane = t & 63;
    if (lane == 0) { red[wave * 2] = s; red[wave * 2 + 1] = sq; }
    __syncthreads();
    float S = red[0] + red[2] + red[4] + red[6];
    float SQ = red[1] + red[3] + red[5] + red[7];
    float mu = S * (1.0f / Dm);
    float var = SQ * (1.0f / Dm) - mu * mu;
    float rstd = rsqrtf(var + 1e-5f);
    int c = t * 2;
    ushort2 o;
    o.x = f2b((v.x - mu) * rstd * gamma[c] + beta[c]);
    o.y = f2b((v.y - mu) * rstd * gamma[c + 1] + beta[c + 1]);
    *(ushort2*)(xn + (size_t)b * Dm + c) = o;
  } else if (b < 10240) {
    int idx = (b - 8192) * 256 + t;
    int l = idx >> 9, k = idx & 511;
    // HW-trig path: abs err ~6e-5, far below the bf16 quantization (0.004) applied to pe.
    float freq = __expf(-0.0359778921f * (float)k);
    float angle = (float)(l - k) * freq;
    pe[idx] = f2b((k & 1) ? __sinf(angle) : __cosf(angle));
  } else {
    int cb = b - 10240;  // 0..1279
    const float* src;
    unsigned short* dst;
    int off;
    if (cb < 768) { src = wq; dst = wqb; off = cb; }
    else if (cb < 1024) { src = wp; dst = wpb; off = cb - 768; }
    else { src = wo; dst = wob; off = cb - 1024; }
    int i = off * 256 + t;
    float4 v = *(const float4*)(src + (size_t)i * 4);
    ushort4 o;
    o.x = f2b(v.x); o.y = f2b(v.y); o.z = f2b(v.z); o.w = f2b(v.w);
    *(ushort4*)(dst + (size_t)i * 4) = o;
  }
}

// ---------------- gemm2: 128x64 asymmetric tile for the QKV (+pos) GEMM (R10, best) ----------------
__global__ __launch_bounds__(256, 6) void gemm2(const unsigned short* __restrict__ Ain,
                                                const unsigned short* __restrict__ Bwin,
                                                const float* __restrict__ biasin,
                                                unsigned short* __restrict__ oq,
                                                unsigned short* __restrict__ ok,
                                                unsigned short* __restrict__ ov,
                                                const unsigned short* __restrict__ A2,
                                                const unsigned short* __restrict__ B2,
                                                float* __restrict__ outf2) {
  int by = blockIdx.y, bx = blockIdx.x;
  int mode = 0;
  const unsigned short* A = Ain;
  const unsigned short* Bw = Bwin;
  const float* bias = biasin;
  float* outf = nullptr;
  if (by < 64) {
    // XCD-locality remap, bijective on 64x24=1536
    int lid = by * 24 + bx;
    int i = lid >> 3;
    by = (lid & 7) * 8 + i / 24;
    bx = i % 24;
  } else {
    if (bx >= 8) return;
    A = A2; Bw = B2; bias = nullptr; outf = outf2; mode = 1; by -= 64;
  }
  const int K = 512;
  __shared__ alignas(16) unsigned short As[128 * 64];
  __shared__ alignas(16) unsigned short Bs[64 * 64];
  const int t = threadIdx.x;
  const int lane = t & 63, w = t >> 6;
  const int c = lane & 15, q8 = lane >> 4;
  const int wm = (w & 1) * 64, wn = (w >> 1) * 32;
  const int m0 = by * 128, n0 = bx * 64;

  f32x4 acc[4][2];
#pragma unroll
  for (int i = 0; i < 4; ++i)
#pragma unroll
    for (int j = 0; j < 2; ++j) acc[i][j] = (f32x4){0.f, 0.f, 0.f, 0.f};

  const int srow = lane >> 3;
  const int sgr = (lane & 7) ^ srow;

  for (int k0 = 0; k0 < K; k0 += 64) {
    __syncthreads();
#pragma unroll
    for (int s = 0; s < 4; ++s) {
      int r = s * 32 + w * 8 + srow;
      GLDS16(A + (size_t)(m0 + r) * K + k0 + sgr * 8, As + (s * 256 + w * 64 + lane) * 8);
    }
#pragma unroll
    for (int s = 0; s < 2; ++s) {
      int r = s * 32 + w * 8 + srow;
      GLDS16(Bw + (size_t)(n0 + r) * K + k0 + sgr * 8, Bs + (s * 256 + w * 64 + lane) * 8);
    }
    __syncthreads();
#pragma unroll
    for (int kk = 0; kk < 2; ++kk) {
      bf16x8 a[4], b[2];
      const int q = kk * 4 + q8;
#pragma unroll
      for (int i = 0; i < 4; ++i) {
        int r = wm + i * 16 + c;
        a[i] = *(const bf16x8*)&As[(r * 8 + (q ^ (r & 7))) * 8];
      }
#pragma unroll
      for (int j = 0; j < 2; ++j) {
        int r = wn + j * 16 + c;
        b[j] = *(const bf16x8*)&Bs[(r * 8 + (q ^ (r & 7))) * 8];
      }
#pragma unroll
      for (int i = 0; i < 4; ++i)
#pragma unroll
        for (int j = 0; j < 2; ++j)
          acc[i][j] = __builtin_amdgcn_mfma_f32_16x16x32_bf16(a[i], b[j], acc[i][j], 0, 0, 0);
    }
  }
#pragma unroll
  for (int i = 0; i < 4; ++i) {
#pragma unroll
    for (int r = 0; r < 4; ++r) {
      int m = m0 + wm + i * 16 + q8 * 4 + r;
#pragma unroll
      for (int j = 0; j < 2; ++j) {
        int n = n0 + wn + j * 16 + c;
        float val = acc[i][j][r] + (bias ? bias[n] : 0.0f);
        if (mode == 0) {
          int part = n >> 9, h = (n >> 6) & 7, dh = n & 63;
          int bb = m >> 10, l = m & 1023;
          size_t idx = (size_t)((bb * 8 + h) * 1024 + l) * 64 + dh;
          if (part == 0) {
            oq[idx] = f2b(val * QSCALE);
          } else if (part == 1) {
            ok[idx] = f2b(val);
          } else {
            union { _Float16 h; unsigned short u; } cv;
            cv.h = (_Float16)val;
            ov[idx] = cv.u;
          }
        } else {
          int h = n >> 6, dh = n & 63;
          outf[(size_t)(h * 1024 + m) * 64 + dh] = val;
        }
      }
    }
  }
}

// ---------------- bf16 MFMA NT GEMM: 64x64 tile (R3-exact) -- out-projection ----------------
__global__ __launch_bounds__(256, 8) void gemm_mfma(const unsigned short* __restrict__ Ain,
                                                    const unsigned short* __restrict__ Bwin,
                                                    const float* __restrict__ biasin,
                                                    float* __restrict__ outfin,
                                                    int K) {
  int by = blockIdx.y, bx = blockIdx.x;
  {
    int NBX = gridDim.x;
    int lid = by * NBX + bx;
    int i = lid >> 3;
    by = (lid & 7) * 16 + i / NBX;
    bx = i % NBX;
  }
  const unsigned short* A = Ain;
  const unsigned short* Bw = Bwin;
  const float* bias = biasin;
  float* outf = outfin;
  __shared__ alignas(16) unsigned short As[64 * 64];
  __shared__ alignas(16) unsigned short Bs[64 * 64];
  const int t = threadIdx.x;
  const int lane = t & 63, w = t >> 6;
  const int c = lane & 15, q8 = lane >> 4;
  const int wm = (w & 1) * 32, wn = (w >> 1) * 32;
  const int m0 = by * 64, n0 = bx * 64;

  f32x4 acc[2][2];
#pragma unroll
  for (int i = 0; i < 2; ++i)
#pragma unroll
    for (int j = 0; j < 2; ++j) acc[i][j] = (f32x4){0.f, 0.f, 0.f, 0.f};

  const int srow = lane >> 3;
  const int sgr = (lane & 7) ^ srow;

  for (int k0 = 0; k0 < K; k0 += 64) {
    __syncthreads();
#pragma unroll
    for (int j = 0; j < 2; ++j) {
      int r = j * 32 + w * 8 + srow;
      GLDS16(A + (size_t)(m0 + r) * K + k0 + sgr * 8, As + (j * 256 + w * 64 + lane) * 8);
      GLDS16(Bw + (size_t)(n0 + r) * K + k0 + sgr * 8, Bs + (j * 256 + w * 64 + lane) * 8);
    }
    __syncthreads();
#pragma unroll
    for (int kk = 0; kk < 2; ++kk) {
      bf16x8 a[2], b[2];
      const int q = kk * 4 + q8;
#pragma unroll
      for (int i = 0; i < 2; ++i) {
        int r = wm + i * 16 + c;
        a[i] = *(const bf16x8*)&As[(r * 8 + (q ^ (r & 7))) * 8];
      }
#pragma unroll
      for (int j = 0; j < 2; ++j) {
        int r = wn + j * 16 + c;
        b[j] = *(const bf16x8*)&Bs[(r * 8 + (q ^ (r & 7))) * 8];
      }
#pragma unroll
      for (int i = 0; i < 2; ++i)
#pragma unroll
        for (int j = 0; j < 2; ++j)
          acc[i][j] = __builtin_amdgcn_mfma_f32_16x16x32_bf16(a[i], b[j], acc[i][j], 0, 0, 0);
    }
  }
#pragma unroll
  for (int i = 0; i < 2; ++i) {
#pragma unroll
    for (int r = 0; r < 4; ++r) {
      int m = m0 + wm + i * 16 + q8 * 4 + r;
#pragma unroll
      for (int j = 0; j < 2; ++j) {
        int n = n0 + wn + j * 16 + c;
        outf[(size_t)m * 512 + n] = acc[i][j][r] + bias[n];
      }
    }
  }
}

// ---------------- prep2: V transpose-permute ONLY (fold fused into flash) ----------------
__global__ __launch_bounds__(256) void prep2(const unsigned short* __restrict__ v,
                                             unsigned short* __restrict__ vt) {
  // V fp16 (b,h,l,d) -> V2 fp16 (b,h,d,perm(l))
  // perm (within 64, for x32 fp16 PV B-frag match):
  //   dst = ((l>>5)&1)*32 + ((l>>2)&3)*8 + ((l>>4)&1)*4 + (l&3)
  __shared__ unsigned short Ts[64 * 68];
  int bb = blockIdx.x;
  int t = threadIdx.x;
  int bh = bb >> 4, lt = bb & 15;
  const unsigned short* vg = v + (size_t)bh * 65536 + lt * 4096;
#pragma unroll
  for (int s = 0; s < 4; ++s) {
    int idx = t + s * 256;
    int r = idx >> 4, c4 = (idx & 15) << 2;
    *(ushort4*)&Ts[r * 68 + c4] = *(const ushort4*)(vg + r * 64 + c4);
  }
  __syncthreads();
#pragma unroll
  for (int s = 0; s < 4; ++s) {
    int idx = t + s * 256;
    int d = idx >> 4, l4 = (idx & 15) << 2;
    ushort4 o;
    o.x = Ts[(l4 + 0) * 68 + d];
    o.y = Ts[(l4 + 1) * 68 + d];
    o.z = Ts[(l4 + 2) * 68 + d];
    o.w = Ts[(l4 + 3) * 68 + d];
    int pb = ((l4 >> 5) & 1) * 32 + ((l4 >> 2) & 3) * 8 + ((l4 >> 4) & 1) * 4;  // l4&3 == 0
    *(ushort4*)(vt + (size_t)bh * 65536 + d * 1024 + lt * 64 + pb) = o;
  }
}

// ---------------- Flash attention v11: v7 structure + FUSED fold (K'=k+pos, bias) ----------------
// S^T = K'.Q^T (bf16 x32), O^T = V^T.P^T (fp16 x32), P stays in registers.
// grid (8, 64), 256 threads; wave w owns queries {w*16+c, 64+w*16+c}.
// Fusion: prefetch loads RAW k + pos (f32); at ds_write time fold K' = k+pos in-register and
// compute bias[key] = (u.k + v.pos)*QSCALE via 3 shfl_xor over the 8 slot-lanes of each row,
// stored to a 128-float LDS array (replaces the staged 4KB bias buffer AND the entire prep2
// fold pass: -16384 blocks, -32MB traffic). Same barriers cover the new LDS writes.
__global__ __launch_bounds__(256, 2) void flash_mfma(const unsigned short* __restrict__ qbf,
                                                     const unsigned short* __restrict__ kbf,
                                                     const unsigned short* __restrict__ vt,
                                                     const float* __restrict__ posb,
                                                     const float* __restrict__ ubias,
                                                     const float* __restrict__ vbias,
                                                     unsigned short* __restrict__ attn_out) {
  __shared__ alignas(16) unsigned short Ks[2][64 * 64];  // key-halves; rows=key, swizzled granules over d
  __shared__ alignas(16) unsigned short Vs[2][64 * 64];  // key-halves; rows=d, swizzled granules over perm(key)
  __shared__ alignas(16) float Bls[128];                 // per-tile bias (pre-scaled)
  const int t = threadIdx.x;
  const int lane = t & 63, w = t >> 6;              // w in [0,4)
  const int c = lane & 15, q8 = lane >> 4;
  const int cc7 = c & 7;
  // XCD-locality remap: lid&7 = XCD; bh = xcd*8 + mid, qt = top  (bijective on 512)
  const int lid = blockIdx.x + (blockIdx.y << 3);
  const int bh = ((lid & 7) << 3) + ((lid >> 3) & 7);
  const int qt = lid >> 6;
  const int hd = bh & 7;  // head
  const unsigned short* qg = qbf + (size_t)bh * 65536;
  const unsigned short* kg = kbf + (size_t)bh * 65536;
  const unsigned short* vg = vt + (size_t)bh * 65536;
  const float* pg = posb + (size_t)hd * 65536;

  // staging geometry: 4 waves x 64 lanes x 2 row-sets cover 64 rows x 8 granules per array half.
  // row = w*16 + j*8 + (lane>>3); slot = lane&7; source granule = slot ^ (row&7).
  const int srow = lane >> 3;
  const int sgr = (lane & 7) ^ srow;
  const int r0 = w * 16 + srow;  // rows r0, r0+8

  // per-lane u/v bias slices at granule sgr (d = sgr*8 .. +8)
  float uarr[8], varr[8];
  {
    f32x4 u0 = *(const f32x4*)(ubias + hd * 64 + sgr * 8);
    f32x4 u1 = *(const f32x4*)(ubias + hd * 64 + sgr * 8 + 4);
    f32x4 v0 = *(const f32x4*)(vbias + hd * 64 + sgr * 8);
    f32x4 v1 = *(const f32x4*)(vbias + hd * 64 + sgr * 8 + 4);
#pragma unroll
    for (int e = 0; e < 4; ++e) {
      uarr[e] = u0[e]; uarr[e + 4] = u1[e];
      varr[e] = v0[e]; varr[e + 4] = v1[e];
    }
  }

  // Q for both query groups, register-resident
  bf16x8 bq[2][2];
#pragma unroll
  for (int g = 0; g < 2; ++g) {
    int qlg = qt * 128 + g * 64 + w * 16 + c;
    bq[g][0] = *(const bf16x8*)(qg + (size_t)qlg * 64 + q8 * 8);
    bq[g][1] = *(const bf16x8*)(qg + (size_t)qlg * 64 + 32 + q8 * 8);
  }

  float m_st[2] = {-INFINITY, -INFINITY};
  float l_st[2] = {0.0f, 0.0f};  // per-lane PARTIAL sums (reduced across q8 in epilogue)
  f32x4 o[2][4];
#pragma unroll
  for (int g = 0; g < 2; ++g)
#pragma unroll
    for (int i = 0; i < 4; ++i) o[g][i] = (f32x4){0.f, 0.f, 0.f, 0.f};

  // prefetch it=0 into VGPRs (raw k, pos f32, V)
  u32x4 pk[2][2], pv[2][2];
  f32x4 pp[2][2][2];
#pragma unroll
  for (int h = 0; h < 2; ++h)
#pragma unroll
    for (int j = 0; j < 2; ++j) {
      int r = r0 + j * 8;
      int key = h * 64 + r;
      pk[h][j] = *(const u32x4*)(kg + (size_t)key * 64 + sgr * 8);
      pv[h][j] = *(const u32x4*)(vg + (size_t)r * 1024 + h * 64 + sgr * 8);
      pp[h][j][0] = *(const f32x4*)(pg + (size_t)key * 64 + sgr * 8);
      pp[h][j][1] = *(const f32x4*)(pg + (size_t)key * 64 + sgr * 8 + 4);
    }

  for (int it = 0; it < 8; ++it) {
    __syncthreads();  // prior iteration's LDS reads done
#pragma unroll
    for (int h = 0; h < 2; ++h)
#pragma unroll
      for (int j = 0; j < 2; ++j) {
        int r = r0 + j * 8;
        // fold K' = k + pos and accumulate bias partial over this granule
        float parr[8];
#pragma unroll
        for (int e = 0; e < 4; ++e) { parr[e] = pp[h][j][0][e]; parr[e + 4] = pp[h][j][1][e]; }
        unsigned int kw[4];
        float part = 0.0f;
#pragma unroll
        for (int e = 0; e < 4; ++e) {
          float k0 = b2f((unsigned short)(pk[h][j][e] & 0xffffu));
          float k1 = b2f((unsigned short)(pk[h][j][e] >> 16));
          float p0 = parr[2 * e], p1 = parr[2 * e + 1];
          part += uarr[2 * e] * k0 + varr[2 * e] * p0 + uarr[2 * e + 1] * k1 + varr[2 * e + 1] * p1;
          kw[e] = (unsigned int)f2b(k0 + p0) | ((unsigned int)f2b(k1 + p1) << 16);
        }
        // reduce bias partial over the 8 slot-lanes holding this row (lanes s*8..s*8+7)
        part += __shfl_xor(part, 1);
        part += __shfl_xor(part, 2);
        part += __shfl_xor(part, 4);
        if ((lane & 7) == 0) Bls[h * 64 + r] = part * QSCALE;
        u32x4 ko = {kw[0], kw[1], kw[2], kw[3]};
        *(u32x4*)&Ks[h][(r * 8 + (lane & 7)) * 8] = ko;
        *(u32x4*)&Vs[h][(r * 8 + (lane & 7)) * 8] = pv[h][j];
      }
    __syncthreads();
    // prefetch next iteration (latency overlaps compute below)
    if (it < 7) {
#pragma unroll
      for (int h = 0; h < 2; ++h)
#pragma unroll
        for (int j = 0; j < 2; ++j) {
          int r = r0 + j * 8;
          int key = (it + 1) * 128 + h * 64 + r;
          pk[h][j] = *(const u32x4*)(kg + (size_t)key * 64 + sgr * 8);
          pv[h][j] = *(const u32x4*)(vg + (size_t)r * 1024 + (it + 1) * 128 + h * 64 + sgr * 8);
          pp[h][j][0] = *(const f32x4*)(pg + (size_t)key * 64 + sgr * 8);
          pp[h][j][1] = *(const f32x4*)(pg + (size_t)key * 64 + sgr * 8 + 4);
        }
    }

    // S^T for both key-halves and both query groups; K-frag + bias reads shared across groups
    f32x4 sc[2][2][4];
#pragma unroll
    for (int h = 0; h < 2; ++h) {
#pragma unroll
      for (int nt = 0; nt < 4; ++nt) {
        f32x4 ci = *(const f32x4*)&Bls[h * 64 + nt * 16 + q8 * 4];
        const int row = nt * 16 + c;
        bf16x8 ak0 = *(const bf16x8*)&Ks[h][(row * 8 + (q8 ^ cc7)) * 8];
        bf16x8 ak1 = *(const bf16x8*)&Ks[h][(row * 8 + ((q8 + 4) ^ cc7)) * 8];
#pragma unroll
        for (int g = 0; g < 2; ++g) {
          f32x4 z = __builtin_amdgcn_mfma_f32_16x16x32_bf16(ak0, bq[g][0], ci, 0, 0, 0);
          sc[g][h][nt] = __builtin_amdgcn_mfma_f32_16x16x32_bf16(ak1, bq[g][1], z, 0, 0, 0);
        }
      }
    }
    // online softmax: local maxima first, then INTERLEAVED cross-lane reductions
    float mx[2];
#pragma unroll
    for (int g = 0; g < 2; ++g) {
      float m = sc[g][0][0][0];
#pragma unroll
      for (int h = 0; h < 2; ++h)
#pragma unroll
        for (int nt = 0; nt < 4; ++nt)
#pragma unroll
          for (int r = 0; r < 4; ++r) m = fmaxf(m, sc[g][h][nt][r]);
      mx[g] = m;
    }
    {
      float s0 = __shfl_xor(mx[0], 16);
      float s1 = __shfl_xor(mx[1], 16);
      mx[0] = fmaxf(mx[0], s0);
      mx[1] = fmaxf(mx[1], s1);
      s0 = __shfl_xor(mx[0], 32);
      s1 = __shfl_xor(mx[1], 32);
      mx[0] = fmaxf(mx[0], s0);
      mx[1] = fmaxf(mx[1], s1);
    }
    // P packed for x32 PV: pf8[g][h][kk] holds keys kk*32 + q8*8 + {tile 2kk: r | tile 2kk+1: 4+r}
    f16x8 pf8[2][2][2];
#pragma unroll
    for (int g = 0; g < 2; ++g) {
      float mn = fmaxf(m_st[g], mx[g]);
      float al = __builtin_amdgcn_exp2f(m_st[g] - mn);
      float su = 0.0f;
#pragma unroll
      for (int h = 0; h < 2; ++h)
#pragma unroll
        for (int nt = 0; nt < 4; ++nt)
#pragma unroll
          for (int r = 0; r < 4; ++r) {
            float p = __builtin_amdgcn_exp2f(sc[g][h][nt][r] - mn);
            su += p;
            pf8[g][h][nt >> 1][((nt & 1) << 2) | r] = (_Float16)p;
          }
      l_st[g] = l_st[g] * al + su;  // per-lane partial (al is query-uniform)
      m_st[g] = mn;
#pragma unroll
      for (int i = 0; i < 4; ++i) o[g][i] *= al;
    }
    // O^T += V^T . P^T  (fp16 x32; V-frag reads shared across groups)
#pragma unroll
    for (int i = 0; i < 4; ++i) {
      const int row = i * 16 + c;
#pragma unroll
      for (int h = 0; h < 2; ++h) {
        f16x8 va = *(const f16x8*)&Vs[h][(row * 8 + (q8 ^ cc7)) * 8];        // granule kk=0
        f16x8 vb = *(const f16x8*)&Vs[h][(row * 8 + ((4 + q8) ^ cc7)) * 8];  // granule kk=1
#pragma unroll
        for (int g = 0; g < 2; ++g) {
          o[g][i] = __builtin_amdgcn_mfma_f32_16x16x32_f16(va, pf8[g][h][0], o[g][i], 0, 0, 0);
          o[g][i] = __builtin_amdgcn_mfma_f32_16x16x32_f16(vb, pf8[g][h][1], o[g][i], 0, 0, 0);
        }
      }
    }
  }
  // epilogue: reduce the deferred l partials across q8 lanes, then write O^T
  float lt0 = l_st[0], lt1 = l_st[1];
  {
    float s0 = __shfl_xor(lt0, 16);
    float s1 = __shfl_xor(lt1, 16);
    lt0 += s0; lt1 += s1;
    s0 = __shfl_xor(lt0, 32);
    s1 = __shfl_xor(lt1, 32);
    lt0 += s0; lt1 += s1;
  }
  const int bidx = bh >> 3;
#pragma unroll
  for (int g = 0; g < 2; ++g) {
    int qlg = qt * 128 + g * 64 + w * 16 + c;
    float inv = 1.0f / (g == 0 ? lt0 : lt1);
    size_t base = (size_t)(bidx * 1024 + qlg) * 512 + hd * 64;
#pragma unroll
    for (int i = 0; i < 4; ++i) {
      ushort4 ov4;
      ov4.x = f2b(o[g][i][0] * inv);
      ov4.y = f2b(o[g][i][1] * inv);
      ov4.z = f2b(o[g][i][2] * inv);
      ov4.w = f2b(o[g][i][3] * inv);
      *(ushort4*)(attn_out + base + i * 16 + q8 * 4) = ov4;
    }
  }
}

extern "C" void kernel_launch(void* const* d_in, const int* in_sizes, int n_in,
                              void* d_out, int out_size, void* d_ws, size_t ws_size,
                              hipStream_t stream) {
  const float* x      = (const float*)d_in[0];
  const float* gamma  = (const float*)d_in[1];
  const float* beta   = (const float*)d_in[2];
  const float* w_qkv  = (const float*)d_in[3];
  const float* b_qkv  = (const float*)d_in[4];
  const float* w_pos  = (const float*)d_in[5];
  const float* w_out  = (const float*)d_in[6];
  const float* b_out  = (const float*)d_in[7];
  const float* u_bias = (const float*)d_in[8];
  const float* v_bias = (const float*)d_in[9];
  float* out = (float*)d_out;

  unsigned short* wsu = (unsigned short*)d_ws;
  unsigned short* xnb   = wsu;                    // 4M ushort
  unsigned short* peb   = wsu + 4194304;          // 512K
  unsigned short* wqkvb = wsu + 4718592;          // 768K
  unsigned short* wposb = wsu + 5505024;          // 256K
  unsigned short* woutb = wsu + 5767168;          // 256K
  unsigned short* qbf   = wsu + 6291456;          // 4M (bf16, pre-scaled)
  unsigned short* kbf   = wsu + 10485760;         // 4M (RAW k bf16; fold fused into flash)
  unsigned short* vbf   = wsu + 14680064;         // 4M (fp16)
  unsigned short* vtb   = wsu + 18874368;         // 4M (fp16, permuted-transposed)
  unsigned short* attnb = wsu + 23068672;         // 4M (bf16)
  float* posb  = (float*)(wsu + 27262976);        // 512K floats

  prep1<<<11520, 256, 0, stream>>>(x, gamma, beta, xnb, peb,
                                   w_qkv, wqkvb, w_pos, wposb, w_out, woutb);
  // QKV GEMM (by<64, 64x24 blocks of 128x64) + pos GEMM (by in [64,72), bx<8) in one dispatch
  gemm2<<<dim3(24, 72), 256, 0, stream>>>(xnb, wqkvb, b_qkv, qbf, kbf, vbf,
                                          peb, wposb, posb);
  prep2<<<1024, 256, 0, stream>>>(vbf, vtb);
  flash_mfma<<<dim3(8, 64), 256, 0, stream>>>(qbf, kbf, vtb, posb, u_bias, v_bias, attnb);
  gemm_mfma<<<dim3(8, 128), 256, 0, stream>>>(attnb, woutb, b_out, out, 512);
}

// Round 12
// 162.123 us; speedup vs baseline: 1.0631x; 1.0631x over previous
//
#include <hip/hip_runtime.h>
#include <math.h>

static constexpr int Bn = 8, Ln = 1024, Dm = 512, Hn = 8, DhN = 64;

typedef short bf16x8 __attribute__((ext_vector_type(8)));
typedef float f32x4 __attribute__((ext_vector_type(4)));
typedef _Float16 f16x4 __attribute__((ext_vector_type(4)));
typedef _Float16 f16x8 __attribute__((ext_vector_type(8)));
typedef unsigned int u32x4 __attribute__((ext_vector_type(4)));
typedef unsigned short u16x8 __attribute__((ext_vector_type(8)));

// 0.125 * log2(e): folds the 1/sqrt(dh) scale AND the exp->exp2 conversion
#define QSCALE 0.1803368801111137f

static __device__ __forceinline__ unsigned short f2b(float f) {
  union { float f; unsigned int u; } x;
  x.f = f;
  unsigned int u = x.u;
  unsigned int r = (u + 0x7FFFu + ((u >> 16) & 1u)) >> 16;  // RNE
  return (unsigned short)r;
}
static __device__ __forceinline__ float b2f(unsigned short u) {
  union { unsigned int u; float f; } x;
  x.u = ((unsigned int)u) << 16;
  return x.f;
}

#define GLDS16(g, l)                                                        \
  __builtin_amdgcn_global_load_lds((const __attribute__((address_space(1))) void*)(g), \
                                   (__attribute__((address_space(3))) void*)(l), 16, 0, 0)

// ---------------- prep1: LayerNorm + PE + weight conversions (one dispatch) ----------------
__global__ __launch_bounds__(256) void prep1(const float* __restrict__ x,
                                             const float* __restrict__ gamma,
                                             const float* __restrict__ beta,
                                             unsigned short* __restrict__ xn,
                                             unsigned short* __restrict__ pe,
                                             const float* __restrict__ wq, unsigned short* __restrict__ wqb,
                                             const float* __restrict__ wp, unsigned short* __restrict__ wpb,
                                             const float* __restrict__ wo, unsigned short* __restrict__ wob) {
  int b = blockIdx.x;
  int t = threadIdx.x;
  if (b < 8192) {
    // LayerNorm row b
    const float2 v = *(const float2*)(x + (size_t)b * Dm + t * 2);
    float s = v.x + v.y;
    float sq = v.x * v.x + v.y * v.y;
#pragma unroll
    for (int off = 32; off > 0; off >>= 1) {
      s += __shfl_down(s, off);
      sq += __shfl_down(sq, off);
    }
    __shared__ float red[8];
    int wave = t >> 6, lane = t & 63;
    if (lane == 0) { red[wave * 2] = s; red[wave * 2 + 1] = sq; }
    __syncthreads();
    float S = red[0] + red[2] + red[4] + red[6];
    float SQ = red[1] + red[3] + red[5] + red[7];
    float mu = S * (1.0f / Dm);
    float var = SQ * (1.0f / Dm) - mu * mu;
    float rstd = rsqrtf(var + 1e-5f);
    int c = t * 2;
    ushort2 o;
    o.x = f2b((v.x - mu) * rstd * gamma[c] + beta[c]);
    o.y = f2b((v.y - mu) * rstd * gamma[c + 1] + beta[c + 1]);
    *(ushort2*)(xn + (size_t)b * Dm + c) = o;
  } else if (b < 10240) {
    int idx = (b - 8192) * 256 + t;
    int l = idx >> 9, k = idx & 511;
    // HW-trig path: abs err ~6e-5, far below the bf16 quantization (0.004) applied to pe.
    float freq = __expf(-0.0359778921f * (float)k);
    float angle = (float)(l - k) * freq;
    pe[idx] = f2b((k & 1) ? __sinf(angle) : __cosf(angle));
  } else {
    int cb = b - 10240;  // 0..1279
    const float* src;
    unsigned short* dst;
    int off;
    if (cb < 768) { src = wq; dst = wqb; off = cb; }
    else if (cb < 1024) { src = wp; dst = wpb; off = cb - 768; }
    else { src = wo; dst = wob; off = cb - 1024; }
    int i = off * 256 + t;
    float4 v = *(const float4*)(src + (size_t)i * 4);
    ushort4 o;
    o.x = f2b(v.x); o.y = f2b(v.y); o.z = f2b(v.z); o.w = f2b(v.w);
    *(ushort4*)(dst + (size_t)i * 4) = o;
  }
}

// ---------------- gemm2: 128x64 asymmetric tile for the QKV (+pos) GEMM (R10, best) ----------------
// mode 1 now writes pos as BF16 (halves the fold pass's pos read traffic; pos is bf16-rounded
// when folded into K' anyway, and the bias's bf16-pos quantization is within tolerance).
__global__ __launch_bounds__(256, 6) void gemm2(const unsigned short* __restrict__ Ain,
                                                const unsigned short* __restrict__ Bwin,
                                                const float* __restrict__ biasin,
                                                unsigned short* __restrict__ oq,
                                                unsigned short* __restrict__ ok,
                                                unsigned short* __restrict__ ov,
                                                const unsigned short* __restrict__ A2,
                                                const unsigned short* __restrict__ B2,
                                                unsigned short* __restrict__ outp) {
  int by = blockIdx.y, bx = blockIdx.x;
  int mode = 0;
  const unsigned short* A = Ain;
  const unsigned short* Bw = Bwin;
  const float* bias = biasin;
  if (by < 64) {
    // XCD-locality remap, bijective on 64x24=1536
    int lid = by * 24 + bx;
    int i = lid >> 3;
    by = (lid & 7) * 8 + i / 24;
    bx = i % 24;
  } else {
    if (bx >= 8) return;
    A = A2; Bw = B2; bias = nullptr; mode = 1; by -= 64;
  }
  const int K = 512;
  __shared__ alignas(16) unsigned short As[128 * 64];
  __shared__ alignas(16) unsigned short Bs[64 * 64];
  const int t = threadIdx.x;
  const int lane = t & 63, w = t >> 6;
  const int c = lane & 15, q8 = lane >> 4;
  const int wm = (w & 1) * 64, wn = (w >> 1) * 32;
  const int m0 = by * 128, n0 = bx * 64;

  f32x4 acc[4][2];
#pragma unroll
  for (int i = 0; i < 4; ++i)
#pragma unroll
    for (int j = 0; j < 2; ++j) acc[i][j] = (f32x4){0.f, 0.f, 0.f, 0.f};

  const int srow = lane >> 3;
  const int sgr = (lane & 7) ^ srow;

  for (int k0 = 0; k0 < K; k0 += 64) {
    __syncthreads();
#pragma unroll
    for (int s = 0; s < 4; ++s) {
      int r = s * 32 + w * 8 + srow;
      GLDS16(A + (size_t)(m0 + r) * K + k0 + sgr * 8, As + (s * 256 + w * 64 + lane) * 8);
    }
#pragma unroll
    for (int s = 0; s < 2; ++s) {
      int r = s * 32 + w * 8 + srow;
      GLDS16(Bw + (size_t)(n0 + r) * K + k0 + sgr * 8, Bs + (s * 256 + w * 64 + lane) * 8);
    }
    __syncthreads();
#pragma unroll
    for (int kk = 0; kk < 2; ++kk) {
      bf16x8 a[4], b[2];
      const int q = kk * 4 + q8;
#pragma unroll
      for (int i = 0; i < 4; ++i) {
        int r = wm + i * 16 + c;
        a[i] = *(const bf16x8*)&As[(r * 8 + (q ^ (r & 7))) * 8];
      }
#pragma unroll
      for (int j = 0; j < 2; ++j) {
        int r = wn + j * 16 + c;
        b[j] = *(const bf16x8*)&Bs[(r * 8 + (q ^ (r & 7))) * 8];
      }
#pragma unroll
      for (int i = 0; i < 4; ++i)
#pragma unroll
        for (int j = 0; j < 2; ++j)
          acc[i][j] = __builtin_amdgcn_mfma_f32_16x16x32_bf16(a[i], b[j], acc[i][j], 0, 0, 0);
    }
  }
#pragma unroll
  for (int i = 0; i < 4; ++i) {
#pragma unroll
    for (int r = 0; r < 4; ++r) {
      int m = m0 + wm + i * 16 + q8 * 4 + r;
#pragma unroll
      for (int j = 0; j < 2; ++j) {
        int n = n0 + wn + j * 16 + c;
        float val = acc[i][j][r] + (bias ? bias[n] : 0.0f);
        if (mode == 0) {
          int part = n >> 9, h = (n >> 6) & 7, dh = n & 63;
          int bb = m >> 10, l = m & 1023;
          size_t idx = (size_t)((bb * 8 + h) * 1024 + l) * 64 + dh;
          if (part == 0) {
            oq[idx] = f2b(val * QSCALE);
          } else if (part == 1) {
            ok[idx] = f2b(val);
          } else {
            union { _Float16 h; unsigned short u; } cv;
            cv.h = (_Float16)val;
            ov[idx] = cv.u;
          }
        } else {
          int h = n >> 6, dh = n & 63;
          outp[(size_t)(h * 1024 + m) * 64 + dh] = f2b(val);
        }
      }
    }
  }
}

// ---------------- bf16 MFMA NT GEMM: 64x64 tile (R3-exact) -- out-projection ----------------
__global__ __launch_bounds__(256, 8) void gemm_mfma(const unsigned short* __restrict__ Ain,
                                                    const unsigned short* __restrict__ Bwin,
                                                    const float* __restrict__ biasin,
                                                    float* __restrict__ outfin,
                                                    int K) {
  int by = blockIdx.y, bx = blockIdx.x;
  {
    int NBX = gridDim.x;
    int lid = by * NBX + bx;
    int i = lid >> 3;
    by = (lid & 7) * 16 + i / NBX;
    bx = i % NBX;
  }
  const unsigned short* A = Ain;
  const unsigned short* Bw = Bwin;
  const float* bias = biasin;
  float* outf = outfin;
  __shared__ alignas(16) unsigned short As[64 * 64];
  __shared__ alignas(16) unsigned short Bs[64 * 64];
  const int t = threadIdx.x;
  const int lane = t & 63, w = t >> 6;
  const int c = lane & 15, q8 = lane >> 4;
  const int wm = (w & 1) * 32, wn = (w >> 1) * 32;
  const int m0 = by * 64, n0 = bx * 64;

  f32x4 acc[2][2];
#pragma unroll
  for (int i = 0; i < 2; ++i)
#pragma unroll
    for (int j = 0; j < 2; ++j) acc[i][j] = (f32x4){0.f, 0.f, 0.f, 0.f};

  const int srow = lane >> 3;
  const int sgr = (lane & 7) ^ srow;

  for (int k0 = 0; k0 < K; k0 += 64) {
    __syncthreads();
#pragma unroll
    for (int j = 0; j < 2; ++j) {
      int r = j * 32 + w * 8 + srow;
      GLDS16(A + (size_t)(m0 + r) * K + k0 + sgr * 8, As + (j * 256 + w * 64 + lane) * 8);
      GLDS16(Bw + (size_t)(n0 + r) * K + k0 + sgr * 8, Bs + (j * 256 + w * 64 + lane) * 8);
    }
    __syncthreads();
#pragma unroll
    for (int kk = 0; kk < 2; ++kk) {
      bf16x8 a[2], b[2];
      const int q = kk * 4 + q8;
#pragma unroll
      for (int i = 0; i < 2; ++i) {
        int r = wm + i * 16 + c;
        a[i] = *(const bf16x8*)&As[(r * 8 + (q ^ (r & 7))) * 8];
      }
#pragma unroll
      for (int j = 0; j < 2; ++j) {
        int r = wn + j * 16 + c;
        b[j] = *(const bf16x8*)&Bs[(r * 8 + (q ^ (r & 7))) * 8];
      }
#pragma unroll
      for (int i = 0; i < 2; ++i)
#pragma unroll
        for (int j = 0; j < 2; ++j)
          acc[i][j] = __builtin_amdgcn_mfma_f32_16x16x32_bf16(a[i], b[j], acc[i][j], 0, 0, 0);
    }
  }
#pragma unroll
  for (int i = 0; i < 2; ++i) {
#pragma unroll
    for (int r = 0; r < 4; ++r) {
      int m = m0 + wm + i * 16 + q8 * 4 + r;
#pragma unroll
      for (int j = 0; j < 2; ++j) {
        int n = n0 + wn + j * 16 + c;
        outf[(size_t)m * 512 + n] = acc[i][j][r] + bias[n];
      }
    }
  }
}

// ---------------- prep2: VECTORIZED fold (K'=k+pos, bias) + V transpose (one dispatch) ----------------
// Fold pass rewritten from scalar 2B/lane (Common-mistake #2, 2-2.5x slow) to short8 16B/lane:
// each thread folds 8 elements of one row; 32 rows/block, 2048 blocks (was 16384 scalar).
// pos now bf16 (half the read traffic). Per-row bias via 3 shfl_xor over the 8 slot-lanes.
__global__ __launch_bounds__(256) void prep2(unsigned short* __restrict__ kbuf,
                                             const unsigned short* __restrict__ posbf,
                                             const float* __restrict__ ub,
                                             const float* __restrict__ vbb,
                                             float* __restrict__ biasout,
                                             const unsigned short* __restrict__ v,
                                             unsigned short* __restrict__ vt) {
  int b = blockIdx.x;
  int t = threadIdx.x;
  if (b < 2048) {
    int g = b * 32 + (t >> 3);  // row in [0, B*H*L)
    int s = t & 7;              // 8B-granule slot within the 64-elem row
    int h = (g >> 10) & 7;
    int m = g & 1023;
    u16x8 kv8 = *(const u16x8*)(kbuf + (size_t)g * 64 + s * 8);
    u16x8 pv8 = *(const u16x8*)(posbf + (size_t)(h * 1024 + m) * 64 + s * 8);
    f32x4 u0 = *(const f32x4*)(ub + h * 64 + s * 8);
    f32x4 u1 = *(const f32x4*)(ub + h * 64 + s * 8 + 4);
    f32x4 v0 = *(const f32x4*)(vbb + h * 64 + s * 8);
    f32x4 v1 = *(const f32x4*)(vbb + h * 64 + s * 8 + 4);
    float part = 0.0f;
    u16x8 o8;
#pragma unroll
    for (int e = 0; e < 8; ++e) {
      float kf = b2f(kv8[e]);
      float pf = b2f(pv8[e]);
      float ue = (e < 4) ? u0[e] : u1[e - 4];
      float ve = (e < 4) ? v0[e] : v1[e - 4];
      part += ue * kf + ve * pf;
      o8[e] = f2b(kf + pf);
    }
    *(u16x8*)(kbuf + (size_t)g * 64 + s * 8) = o8;
    part += __shfl_xor(part, 1);
    part += __shfl_xor(part, 2);
    part += __shfl_xor(part, 4);
    if (s == 0) biasout[g] = part * QSCALE;
  } else {
    // V fp16 (b,h,l,d) -> V2 fp16 (b,h,d,perm(l))
    // perm (within 64, for x32 fp16 PV B-frag match):
    //   dst = ((l>>5)&1)*32 + ((l>>2)&3)*8 + ((l>>4)&1)*4 + (l&3)
    __shared__ unsigned short Ts[64 * 68];
    int bb = b - 2048;
    int bh = bb >> 4, lt = bb & 15;
    const unsigned short* vg = v + (size_t)bh * 65536 + lt * 4096;
#pragma unroll
    for (int s = 0; s < 4; ++s) {
      int idx = t + s * 256;
      int r = idx >> 4, c4 = (idx & 15) << 2;
      *(ushort4*)&Ts[r * 68 + c4] = *(const ushort4*)(vg + r * 64 + c4);
    }
    __syncthreads();
#pragma unroll
    for (int s = 0; s < 4; ++s) {
      int idx = t + s * 256;
      int d = idx >> 4, l4 = (idx & 15) << 2;
      ushort4 o;
      o.x = Ts[(l4 + 0) * 68 + d];
      o.y = Ts[(l4 + 1) * 68 + d];
      o.z = Ts[(l4 + 2) * 68 + d];
      o.w = Ts[(l4 + 3) * 68 + d];
      int pb = ((l4 >> 5) & 1) * 32 + ((l4 >> 2) & 3) * 8 + ((l4 >> 4) & 1) * 4;  // l4&3 == 0
      *(ushort4*)(vt + (size_t)bh * 65536 + d * 1024 + lt * 64 + pb) = o;
    }
  }
}

// ---------------- Flash attention v7 (empirical best ~32us): XCD-local K/V reuse ----------------
// S^T = K'.Q^T (bf16 x32), O^T = V^T.P^T (fp16 x32), P stays in registers.
// grid (8, 64), 256 threads; wave w owns queries {w*16+c, 64+w*16+c}.
// Bijective XCD swizzle: all 8 qt-blocks sharing one bh's K/V (256 KB) land on ONE XCD;
// per-XCD set = 8 bh x 256 KB = 2 MB < 4 MB L2 (R7 verified: FETCH 72->18MB).
// Ledger: v8 (2x TLP+setprio) ~0/-, v9 (dbuf 1-barrier) -11us, v10 (zero-LDS) -27us,
// v11 (fused fold) -12us -- the 2-barrier reg-prefetch LDS structure is the measured optimum.
__global__ __launch_bounds__(256, 2) void flash_mfma(const unsigned short* __restrict__ qbf,
                                                     const unsigned short* __restrict__ kbf,
                                                     const unsigned short* __restrict__ vt,
                                                     const float* __restrict__ bias,
                                                     unsigned short* __restrict__ attn_out) {
  __shared__ alignas(16) unsigned short Ks[2][64 * 64];  // key-halves; rows=key, swizzled granules over d
  __shared__ alignas(16) unsigned short Vs[2][64 * 64];  // key-halves; rows=d, swizzled granules over perm(key)
  __shared__ alignas(16) float Bls[1024];
  const int t = threadIdx.x;
  const int lane = t & 63, w = t >> 6;              // w in [0,4)
  const int c = lane & 15, q8 = lane >> 4;
  const int cc7 = c & 7;
  // XCD-locality remap: lid&7 = XCD; bh = xcd*8 + mid, qt = top  (bijective on 512)
  const int lid = blockIdx.x + (blockIdx.y << 3);
  const int bh = ((lid & 7) << 3) + ((lid >> 3) & 7);
  const int qt = lid >> 6;
  const unsigned short* qg = qbf + (size_t)bh * 65536;
  const unsigned short* kg = kbf + (size_t)bh * 65536;
  const unsigned short* vg = vt + (size_t)bh * 65536;
  const float* bg = bias + (size_t)bh * 1024;

  // stage bias once (4 KB): 256 threads x 16 B
  GLDS16(bg + t * 4, Bls + t * 4);

  // Q for both query groups, register-resident
  bf16x8 bq[2][2];
#pragma unroll
  for (int g = 0; g < 2; ++g) {
    int qlg = qt * 128 + g * 64 + w * 16 + c;
    bq[g][0] = *(const bf16x8*)(qg + (size_t)qlg * 64 + q8 * 8);
    bq[g][1] = *(const bf16x8*)(qg + (size_t)qlg * 64 + 32 + q8 * 8);
  }

  float m_st[2] = {-INFINITY, -INFINITY};
  float l_st[2] = {0.0f, 0.0f};  // per-lane PARTIAL sums (reduced across q8 in epilogue)
  f32x4 o[2][4];
#pragma unroll
  for (int g = 0; g < 2; ++g)
#pragma unroll
    for (int i = 0; i < 4; ++i) o[g][i] = (f32x4){0.f, 0.f, 0.f, 0.f};

  // staging geometry: 4 waves x 64 lanes x 2 row-sets cover 64 rows x 8 granules per array half.
  // row = w*16 + j*8 + (lane>>3); slot = lane&7; source granule = slot ^ (row&7).
  const int srow = lane >> 3;
  const int sgr = (lane & 7) ^ srow;
  const int r0 = w * 16 + srow;  // rows r0, r0+8

  // prefetch it=0 into VGPRs
  u32x4 pk[2][2], pv[2][2];
#pragma unroll
  for (int h = 0; h < 2; ++h)
#pragma unroll
    for (int j = 0; j < 2; ++j) {
      int r = r0 + j * 8;
      pk[h][j] = *(const u32x4*)(kg + (size_t)(h * 64 + r) * 64 + sgr * 8);
      pv[h][j] = *(const u32x4*)(vg + (size_t)r * 1024 + h * 64 + sgr * 8);
    }

  for (int it = 0; it < 8; ++it) {
    __syncthreads();  // prior iteration's LDS reads done
#pragma unroll
    for (int h = 0; h < 2; ++h)
#pragma unroll
      for (int j = 0; j < 2; ++j) {
        int r = r0 + j * 8;
        *(u32x4*)&Ks[h][(r * 8 + (lane & 7)) * 8] = pk[h][j];
        *(u32x4*)&Vs[h][(r * 8 + (lane & 7)) * 8] = pv[h][j];
      }
    __syncthreads();
    // prefetch next iteration (latency overlaps compute below)
    if (it < 7) {
#pragma unroll
      for (int h = 0; h < 2; ++h)
#pragma unroll
        for (int j = 0; j < 2; ++j) {
          int r = r0 + j * 8;
          pk[h][j] = *(const u32x4*)(kg + (size_t)((it + 1) * 128 + h * 64 + r) * 64 + sgr * 8);
          pv[h][j] = *(const u32x4*)(vg + (size_t)r * 1024 + (it + 1) * 128 + h * 64 + sgr * 8);
        }
    }

    // S^T for both key-halves and both query groups; K-frag + bias reads shared across groups
    f32x4 sc[2][2][4];
#pragma unroll
    for (int h = 0; h < 2; ++h) {
#pragma unroll
      for (int nt = 0; nt < 4; ++nt) {
        f32x4 ci = *(const f32x4*)&Bls[it * 128 + h * 64 + nt * 16 + q8 * 4];
        const int row = nt * 16 + c;
        bf16x8 ak0 = *(const bf16x8*)&Ks[h][(row * 8 + (q8 ^ cc7)) * 8];
        bf16x8 ak1 = *(const bf16x8*)&Ks[h][(row * 8 + ((q8 + 4) ^ cc7)) * 8];
#pragma unroll
        for (int g = 0; g < 2; ++g) {
          f32x4 z = __builtin_amdgcn_mfma_f32_16x16x32_bf16(ak0, bq[g][0], ci, 0, 0, 0);
          sc[g][h][nt] = __builtin_amdgcn_mfma_f32_16x16x32_bf16(ak1, bq[g][1], z, 0, 0, 0);
        }
      }
    }
    // online softmax: local maxima first, then INTERLEAVED cross-lane reductions
    float mx[2];
#pragma unroll
    for (int g = 0; g < 2; ++g) {
      float m = sc[g][0][0][0];
#pragma unroll
      for (int h = 0; h < 2; ++h)
#pragma unroll
        for (int nt = 0; nt < 4; ++nt)
#pragma unroll
          for (int r = 0; r < 4; ++r) m = fmaxf(m, sc[g][h][nt][r]);
      mx[g] = m;
    }
    {
      float s0 = __shfl_xor(mx[0], 16);
      float s1 = __shfl_xor(mx[1], 16);
      mx[0] = fmaxf(mx[0], s0);
      mx[1] = fmaxf(mx[1], s1);
      s0 = __shfl_xor(mx[0], 32);
      s1 = __shfl_xor(mx[1], 32);
      mx[0] = fmaxf(mx[0], s0);
      mx[1] = fmaxf(mx[1], s1);
    }
    // P packed for x32 PV: pf8[g][h][kk] holds keys kk*32 + q8*8 + {tile 2kk: r | tile 2kk+1: 4+r}
    f16x8 pf8[2][2][2];
#pragma unroll
    for (int g = 0; g < 2; ++g) {
      float mn = fmaxf(m_st[g], mx[g]);
      float al = __builtin_amdgcn_exp2f(m_st[g] - mn);
      float su = 0.0f;
#pragma unroll
      for (int h = 0; h < 2; ++h)
#pragma unroll
        for (int nt = 0; nt < 4; ++nt)
#pragma unroll
          for (int r = 0; r < 4; ++r) {
            float p = __builtin_amdgcn_exp2f(sc[g][h][nt][r] - mn);
            su += p;
            pf8[g][h][nt >> 1][((nt & 1) << 2) | r] = (_Float16)p;
          }
      l_st[g] = l_st[g] * al + su;  // per-lane partial (al is query-uniform)
      m_st[g] = mn;
#pragma unroll
      for (int i = 0; i < 4; ++i) o[g][i] *= al;
    }
    // O^T += V^T . P^T  (fp16 x32; V-frag reads shared across groups)
#pragma unroll
    for (int i = 0; i < 4; ++i) {
      const int row = i * 16 + c;
#pragma unroll
      for (int h = 0; h < 2; ++h) {
        f16x8 va = *(const f16x8*)&Vs[h][(row * 8 + (q8 ^ cc7)) * 8];        // granule kk=0
        f16x8 vb = *(const f16x8*)&Vs[h][(row * 8 + ((4 + q8) ^ cc7)) * 8];  // granule kk=1
#pragma unroll
        for (int g = 0; g < 2; ++g) {
          o[g][i] = __builtin_amdgcn_mfma_f32_16x16x32_f16(va, pf8[g][h][0], o[g][i], 0, 0, 0);
          o[g][i] = __builtin_amdgcn_mfma_f32_16x16x32_f16(vb, pf8[g][h][1], o[g][i], 0, 0, 0);
        }
      }
    }
  }
  // epilogue: reduce the deferred l partials across q8 lanes, then write O^T
  float lt0 = l_st[0], lt1 = l_st[1];
  {
    float s0 = __shfl_xor(lt0, 16);
    float s1 = __shfl_xor(lt1, 16);
    lt0 += s0; lt1 += s1;
    s0 = __shfl_xor(lt0, 32);
    s1 = __shfl_xor(lt1, 32);
    lt0 += s0; lt1 += s1;
  }
  const int bidx = bh >> 3, h = bh & 7;
#pragma unroll
  for (int g = 0; g < 2; ++g) {
    int qlg = qt * 128 + g * 64 + w * 16 + c;
    float inv = 1.0f / (g == 0 ? lt0 : lt1);
    size_t base = (size_t)(bidx * 1024 + qlg) * 512 + h * 64;
#pragma unroll
    for (int i = 0; i < 4; ++i) {
      ushort4 ov4;
      ov4.x = f2b(o[g][i][0] * inv);
      ov4.y = f2b(o[g][i][1] * inv);
      ov4.z = f2b(o[g][i][2] * inv);
      ov4.w = f2b(o[g][i][3] * inv);
      *(ushort4*)(attn_out + base + i * 16 + q8 * 4) = ov4;
    }
  }
}

extern "C" void kernel_launch(void* const* d_in, const int* in_sizes, int n_in,
                              void* d_out, int out_size, void* d_ws, size_t ws_size,
                              hipStream_t stream) {
  const float* x      = (const float*)d_in[0];
  const float* gamma  = (const float*)d_in[1];
  const float* beta   = (const float*)d_in[2];
  const float* w_qkv  = (const float*)d_in[3];
  const float* b_qkv  = (const float*)d_in[4];
  const float* w_pos  = (const float*)d_in[5];
  const float* w_out  = (const float*)d_in[6];
  const float* b_out  = (const float*)d_in[7];
  const float* u_bias = (const float*)d_in[8];
  const float* v_bias = (const float*)d_in[9];
  float* out = (float*)d_out;

  unsigned short* wsu = (unsigned short*)d_ws;
  unsigned short* xnb   = wsu;                    // 4M ushort
  unsigned short* peb   = wsu + 4194304;          // 512K
  unsigned short* wqkvb = wsu + 4718592;          // 768K
  unsigned short* wposb = wsu + 5505024;          // 256K
  unsigned short* woutb = wsu + 5767168;          // 256K
  unsigned short* qbf   = wsu + 6291456;          // 4M (bf16, pre-scaled)
  unsigned short* kbf   = wsu + 10485760;         // 4M (k bf16 -> K' after fold)
  unsigned short* vbf   = wsu + 14680064;         // 4M (fp16)
  unsigned short* vtb   = wsu + 18874368;         // 4M (fp16, permuted-transposed)
  unsigned short* attnb = wsu + 23068672;         // 4M (bf16)
  unsigned short* posbf = wsu + 27262976;         // 512K ushort (pos bf16)
  float* biasb = (float*)(wsu + 28311552);        // 64K floats (pre-scaled)

  prep1<<<11520, 256, 0, stream>>>(x, gamma, beta, xnb, peb,
                                   w_qkv, wqkvb, w_pos, wposb, w_out, woutb);
  // QKV GEMM (by<64, 64x24 blocks of 128x64) + pos GEMM (by in [64,72), bx<8) in one dispatch
  gemm2<<<dim3(24, 72), 256, 0, stream>>>(xnb, wqkvb, b_qkv, qbf, kbf, vbf,
                                          peb, wposb, posbf);
  prep2<<<3072, 256, 0, stream>>>(kbf, posbf, u_bias, v_bias, biasb, vbf, vtb);
  flash_mfma<<<dim3(8, 64), 256, 0, stream>>>(qbf, kbf, vtb, biasb, attnb);
  gemm_mfma<<<dim3(8, 128), 256, 0, stream>>>(attnb, woutb, b_out, out, 512);
}